// Round 2
// baseline (1070.585 us; speedup 1.0000x reference)
//
#include <hip/hip_runtime.h>
#include <cstdint>
#include <cstddef>

#define SEQ   2048
#define NH    16
#define DKD   64
#define DM    1024

typedef __attribute__((ext_vector_type(8))) short bf16x8;
typedef __attribute__((ext_vector_type(4))) short bf16x4;
typedef __attribute__((ext_vector_type(4))) float f32x4;
typedef unsigned short u16;

__device__ __forceinline__ u16 f2bf(float f) {
    union { float f; unsigned u; } v; v.f = f;
    unsigned r = v.u + 0x7fff + ((v.u >> 16) & 1);   // RNE
    return (u16)(r >> 16);
}
__device__ __forceinline__ float bf2f(u16 b) {
    union { unsigned u; float f; } v; v.u = ((unsigned)b) << 16;
    return v.f;
}

// ---------------------------------------------------------------------------
// C[M,N] = A[M,K] * B[N,K]^T   (fp32 in -> bf16 LDS -> MFMA fp32 acc)
// M=4096, K=1024, N=1024. 128x128 tile, 256 thr = 4 waves, each 64x64.
// MODE 0: Q  -> bf16 dst[b,h,s,dk]  (scaled by 1/8)
// MODE 1: K  -> bf16 dst[b,h,s,dk]
// MODE 2: V  -> bf16 dst[b,h,dk,s]  (transposed for PV B-operand)
// MODE 3: out-> fp32 dst[row,col] + bias[col]
// ---------------------------------------------------------------------------
template<int MODE>
__global__ __launch_bounds__(256, 2)
void gemm_bt(const float* __restrict__ A, const float* __restrict__ Bm,
             void* __restrict__ dstv, const float* __restrict__ bias) {
    __shared__ u16 As[128][72];   // 144B row stride: 8/16B aligned accesses ok
    __shared__ u16 Bs[128][72];

    const int t    = threadIdx.x;
    const int m0   = blockIdx.y * 128;
    const int n0   = blockIdx.x * 128;
    const int w    = t >> 6;
    const int lane = t & 63;
    const int l16  = lane & 15;
    const int quad = lane >> 4;
    const int wr   = (w >> 1) * 64;
    const int wc   = (w & 1) * 64;

    f32x4 acc[4][4];
#pragma unroll
    for (int i = 0; i < 4; i++)
#pragma unroll
        for (int j = 0; j < 4; j++) {
            f32x4 z = {0.f, 0.f, 0.f, 0.f};
            acc[i][j] = z;
        }

    for (int k0 = 0; k0 < 1024; k0 += 64) {
#pragma unroll
        for (int i = 0; i < 8; i++) {
            int c  = t + 256 * i;          // 0..2047
            int r  = c >> 4;               // 0..127
            int c4 = (c & 15) * 4;         // 0..60
            f32x4 av = *(const f32x4*)&A [(size_t)(m0 + r) * 1024 + k0 + c4];
            f32x4 bv = *(const f32x4*)&Bm[(size_t)(n0 + r) * 1024 + k0 + c4];
            bf16x4 ab, bb;
#pragma unroll
            for (int j = 0; j < 4; j++) { ab[j] = (short)f2bf(av[j]); bb[j] = (short)f2bf(bv[j]); }
            *(bf16x4*)&As[r][c4] = ab;
            *(bf16x4*)&Bs[r][c4] = bb;
        }
        __syncthreads();
#pragma unroll
        for (int ks = 0; ks < 2; ks++) {
            bf16x8 af[4], bfr[4];
#pragma unroll
            for (int i = 0; i < 4; i++)
                af[i] = *(const bf16x8*)&As[wr + i * 16 + l16][ks * 32 + quad * 8];
#pragma unroll
            for (int j = 0; j < 4; j++)
                bfr[j] = *(const bf16x8*)&Bs[wc + j * 16 + l16][ks * 32 + quad * 8];
#pragma unroll
            for (int i = 0; i < 4; i++)
#pragma unroll
                for (int j = 0; j < 4; j++)
                    acc[i][j] = __builtin_amdgcn_mfma_f32_16x16x32_bf16(
                        af[i], bfr[j], acc[i][j], 0, 0, 0);
        }
        __syncthreads();
    }

    u16*   dst16 = (u16*)dstv;
    float* dstf  = (float*)dstv;
#pragma unroll
    for (int i = 0; i < 4; i++) {
#pragma unroll
        for (int j = 0; j < 4; j++) {
#pragma unroll
            for (int r = 0; r < 4; r++) {
                int row = m0 + wr + i * 16 + quad * 4 + r;   // C layout: row=quad*4+reg
                int col = n0 + wc + j * 16 + l16;            //           col=lane&15
                float v = acc[i][j][r];
                if (MODE == 0 || MODE == 1) {
                    int b = row >> 11, s = row & 2047, h = col >> 6, dk = col & 63;
                    if (MODE == 0) v *= 0.125f;              // 1/sqrt(64), exact pow2
                    dst16[((size_t)((b * 16 + h) * 2048 + s)) * 64 + dk] = f2bf(v);
                } else if (MODE == 2) {
                    int b = row >> 11, s = row & 2047, h = col >> 6, dk = col & 63;
                    dst16[((size_t)((b * 16 + h) * 64 + dk)) * 2048 + s] = f2bf(v);
                } else {
                    v += bias[col];
                    dstf[(size_t)row * 1024 + col] = v;
                }
            }
        }
    }
}

// ---------------------------------------------------------------------------
// Two-pass attention per (b,h, 64-row Q tile).
// Pass A: exact row max m and denom l (online, MFMA scores, never stored).
// Pass B: recompute scores, p = exp(s-m)/l, write attn fp32 (coalesced via
//         LDS), accumulate O = P·V with MFMA (P routed through LDS:
//         C-layout -> A-operand layout).
// Q pre-scaled by 1/8 in projection. V stored [dk][s] so B-frag is b128.
// ---------------------------------------------------------------------------
__global__ __launch_bounds__(256, 2)
void attn_kernel(const u16* __restrict__ Qw, const u16* __restrict__ Kw,
                 const u16* __restrict__ Vtw,
                 float* __restrict__ attn_out, float* __restrict__ ctx_out) {
    __shared__ u16 Qs[64][72];      //  9216 B
    __shared__ u16 KVs[128][72];    // 18432 B (reused for Vt[64][136] = 8704 elems)
    __shared__ u16 Ps[64][136];     // 17408 B
    u16 (*Vts)[136] = (u16(*)[136])&KVs[0][0];

    const int t    = threadIdx.x;
    const int bh   = blockIdx.y;
    const int q0   = blockIdx.x * 64;
    const int w    = t >> 6;
    const int lane = t & 63;
    const int l16  = lane & 15;
    const int quad = lane >> 4;

    const u16* Qh = Qw  + (size_t)bh * SEQ * DKD;
    const u16* Kh = Kw  + (size_t)bh * SEQ * DKD;
    const u16* Vh = Vtw + (size_t)bh * DKD * SEQ;

    // stage Q tile (64 x 64)
#pragma unroll
    for (int i = 0; i < 2; i++) {
        int c  = t + 256 * i;
        int r  = c >> 3;
        int c8 = (c & 7) * 8;
        *(bf16x8*)&Qs[r][c8] = *(const bf16x8*)&Qh[(size_t)(q0 + r) * 64 + c8];
    }

    float m[4], l[4];
#pragma unroll
    for (int r = 0; r < 4; r++) { m[r] = -1e30f; l[r] = 0.f; }

    // ---------------- pass A: row stats ----------------
    for (int kt = 0; kt < 16; kt++) {
        __syncthreads();                       // prev KVs reads done (and Q stage @kt=0)
#pragma unroll
        for (int i = 0; i < 4; i++) {
            int c  = t + 256 * i;
            int r  = c >> 3;
            int c8 = (c & 7) * 8;
            *(bf16x8*)&KVs[r][c8] = *(const bf16x8*)&Kh[(size_t)(kt * 128 + r) * 64 + c8];
        }
        __syncthreads();

        f32x4 s[8];
#pragma unroll
        for (int j = 0; j < 8; j++) { f32x4 z = {0.f,0.f,0.f,0.f}; s[j] = z; }
#pragma unroll
        for (int ks = 0; ks < 2; ks++) {
            bf16x8 a = *(const bf16x8*)&Qs[w * 16 + l16][ks * 32 + quad * 8];
#pragma unroll
            for (int j = 0; j < 8; j++) {
                bf16x8 b = *(const bf16x8*)&KVs[j * 16 + l16][ks * 32 + quad * 8];
                s[j] = __builtin_amdgcn_mfma_f32_16x16x32_bf16(a, b, s[j], 0, 0, 0);
            }
        }
#pragma unroll
        for (int r = 0; r < 4; r++) {
            float mt = s[0][r];
#pragma unroll
            for (int j = 1; j < 8; j++) mt = fmaxf(mt, s[j][r]);
#pragma unroll
            for (int d = 1; d < 16; d <<= 1) mt = fmaxf(mt, __shfl_xor(mt, d, 64));
            float mn = fmaxf(m[r], mt);
            float sum = 0.f;
#pragma unroll
            for (int j = 0; j < 8; j++) sum += __expf(s[j][r] - mn);
#pragma unroll
            for (int d = 1; d < 16; d <<= 1) sum += __shfl_xor(sum, d, 64);
            l[r] = l[r] * __expf(m[r] - mn) + sum;
            m[r] = mn;
        }
    }

    float invl[4];
#pragma unroll
    for (int r = 0; r < 4; r++) invl[r] = 1.f / l[r];

    f32x4 o[4];
#pragma unroll
    for (int jo = 0; jo < 4; jo++) { f32x4 z = {0.f,0.f,0.f,0.f}; o[jo] = z; }

    // ---------------- pass B: write attn + accumulate O ----------------
    for (int kt = 0; kt < 16; kt++) {
        __syncthreads();                       // prev Ps/Vts reads done
#pragma unroll
        for (int i = 0; i < 4; i++) {
            int c  = t + 256 * i;
            int r  = c >> 3;
            int c8 = (c & 7) * 8;
            *(bf16x8*)&KVs[r][c8] = *(const bf16x8*)&Kh[(size_t)(kt * 128 + r) * 64 + c8];
        }
        __syncthreads();

        f32x4 s[8];
#pragma unroll
        for (int j = 0; j < 8; j++) { f32x4 z = {0.f,0.f,0.f,0.f}; s[j] = z; }
#pragma unroll
        for (int ks = 0; ks < 2; ks++) {
            bf16x8 a = *(const bf16x8*)&Qs[w * 16 + l16][ks * 32 + quad * 8];
#pragma unroll
            for (int j = 0; j < 8; j++) {
                bf16x8 b = *(const bf16x8*)&KVs[j * 16 + l16][ks * 32 + quad * 8];
                s[j] = __builtin_amdgcn_mfma_f32_16x16x32_bf16(a, b, s[j], 0, 0, 0);
            }
        }
        __syncthreads();                       // all score reads of KVs done

        // p -> LDS (C-layout scatter, 2B writes, 2-way alias only)
#pragma unroll
        for (int j = 0; j < 8; j++)
#pragma unroll
            for (int r = 0; r < 4; r++) {
                float p = __expf(s[j][r] - m[r]) * invl[r];
                Ps[w * 16 + quad * 4 + r][j * 16 + l16] = f2bf(p);
            }
        // stage Vt tile (64 dk-rows x 128 seq) into KVs
#pragma unroll
        for (int i = 0; i < 4; i++) {
            int c  = t + 256 * i;
            int r  = c >> 4;
            int c8 = (c & 15) * 8;
            *(bf16x8*)&Vts[r][c8] = *(const bf16x8*)&Vh[(size_t)r * 2048 + kt * 128 + c8];
        }
        __syncthreads();                       // Ps + Vts ready

        // coalesced fp32 attn write: 64 rows x 128 cols, float4/lane
#pragma unroll
        for (int i = 0; i < 8; i++) {
            int c  = t + 256 * i;              // 0..2047
            int r  = c >> 5;                   // 0..63
            int c4 = (c & 31) * 4;             // 0..124
            bf16x4 pv = *(const bf16x4*)&Ps[r][c4];
            f32x4 o4;
#pragma unroll
            for (int j = 0; j < 4; j++) o4[j] = bf2f((u16)pv[j]);
            *(f32x4*)&attn_out[((size_t)(bh * 2048 + q0 + r)) * 2048 + kt * 128 + c4] = o4;
        }

        // O += P·V
        bf16x8 pa[4];
#pragma unroll
        for (int ks = 0; ks < 4; ks++)
            pa[ks] = *(const bf16x8*)&Ps[w * 16 + l16][ks * 32 + quad * 8];
#pragma unroll
        for (int jo = 0; jo < 4; jo++)
#pragma unroll
            for (int ks = 0; ks < 4; ks++) {
                bf16x8 vb = *(const bf16x8*)&Vts[jo * 16 + l16][ks * 32 + quad * 8];
                o[jo] = __builtin_amdgcn_mfma_f32_16x16x32_bf16(pa[ks], vb, o[jo], 0, 0, 0);
            }
    }

    // write ctx [B,S,D] fp32
    const int b = bh >> 4, h = bh & 15;
#pragma unroll
    for (int jo = 0; jo < 4; jo++)
#pragma unroll
        for (int r = 0; r < 4; r++) {
            int srow = q0 + w * 16 + quad * 4 + r;
            int dcol = h * 64 + jo * 16 + l16;
            ctx_out[((size_t)(b * 2048 + srow)) * 1024 + dcol] = o[jo][r];
        }
}

// ---------------------------------------------------------------------------
extern "C" void kernel_launch(void* const* d_in, const int* in_sizes, int n_in,
                              void* d_out, int out_size, void* d_ws, size_t ws_size,
                              hipStream_t stream) {
    (void)in_sizes; (void)n_in; (void)out_size; (void)ws_size;

    const float* q  = (const float*)d_in[0];
    const float* k  = (const float*)d_in[1];
    const float* v  = (const float*)d_in[2];
    const float* wq = (const float*)d_in[3];
    const float* wk = (const float*)d_in[4];
    const float* wv = (const float*)d_in[5];
    const float* wo = (const float*)d_in[6];
    const float* bo = (const float*)d_in[7];

    float* out  = (float*)d_out;                   // [2,2048,1024] fp32
    float* attn = out + (size_t)4194304;           // [2,16,2048,2048] fp32

    u16*   Qw  = (u16*)d_ws;                       // [B,H,S,64] bf16   8 MB
    u16*   Kw  = Qw + (size_t)4194304;             // [B,H,S,64] bf16   8 MB
    u16*   Vtw = Kw + (size_t)4194304;             // [B,H,64,S] bf16   8 MB
    float* ctx = (float*)(Vtw + (size_t)4194304);  // [B,S,D]    fp32  16 MB

    dim3 blk(256);
    dim3 gp(8, 32);                                // N/128, M/128
    gemm_bt<0><<<gp, blk, 0, stream>>>(q, wq, (void*)Qw, nullptr);
    gemm_bt<1><<<gp, blk, 0, stream>>>(k, wk, (void*)Kw, nullptr);
    gemm_bt<2><<<gp, blk, 0, stream>>>(v, wv, (void*)Vtw, nullptr);

    attn_kernel<<<dim3(32, 32), blk, 0, stream>>>(Qw, Kw, Vtw, attn, ctx);

    gemm_bt<3><<<gp, blk, 0, stream>>>(ctx, wo, (void*)out, bo);
}